// Round 15
// baseline (224.501 us; speedup 1.0000x reference)
//
#include <hip/hip_runtime.h>
#include <hip/hip_bf16.h>
#include <math.h>

// ---------- common helpers ----------
typedef float f32x4 __attribute__((ext_vector_type(4)));
typedef __bf16 bf16x8 __attribute__((ext_vector_type(8)));

__device__ inline f32x4 mfma16(bf16x8 a, bf16x8 b, f32x4 c) {
    return __builtin_amdgcn_mfma_f32_16x16x32_bf16(a, b, c, 0, 0, 0);
}
__device__ inline unsigned short f2bf(float f) {   // RNE f32 -> bf16
    union { float f; unsigned u; } v; v.f = f;
    unsigned r = v.u + 0x7fffu + ((v.u >> 16) & 1u);
    return (unsigned short)(r >> 16);
}
__device__ inline float bf2f(unsigned short b) {
    union { unsigned u; float f; } v; v.u = ((unsigned)b) << 16;
    return v.f;
}
__device__ inline unsigned pack2(float a, float b) {
    return (unsigned)f2bf(a) | ((unsigned)f2bf(b) << 16);
}
__device__ inline f32x4 vzero() { f32x4 z = {0.f, 0.f, 0.f, 0.f}; return z; }

// async global->LDS, 16B per lane; LDS dest = wave-uniform base + lane*16 (m97/m104)
#define GLD16(gptr, lptr)                                                            \
    __builtin_amdgcn_global_load_lds(                                                \
        (const __attribute__((address_space(1))) unsigned int*)(const void*)(gptr),  \
        (__attribute__((address_space(3))) unsigned int*)(void*)(lptr), 16, 0, 0)

// ---------- convert x, Wqkv (f32, proven R3-R14) -> bf16; 3584 blocks exact ----------
__global__ __launch_bounds__(256)
void convert_xw(const float* __restrict__ x, const float* __restrict__ wqkv,
                unsigned short* __restrict__ xb, unsigned short* __restrict__ wqkvb)
{
    int i = blockIdx.x * 256 + threadIdx.x;   // < 917504
    const float* src; unsigned short* dst; int off;
    if (i < 524288) { src = x;    dst = xb;    off = i; }
    else            { src = wqkv; dst = wqkvb; off = i - 524288; }
    const float4* p = (const float4*)src + (size_t)off * 2;
    float4 f0 = p[0], f1 = p[1];
    uint4 o;
    o.x = pack2(f0.x, f0.y); o.y = pack2(f0.z, f0.w);
    o.z = pack2(f1.x, f1.y); o.w = pack2(f1.z, f1.w);
    ((uint4*)dst)[off] = o;
}

// ---------- GEMM: C[M,N] = A[M,K] * W[N,K]^T  (R12-proven, dim3 grid) ----------
template<int MI, int C32, int WPB>
__global__ __launch_bounds__(256, WPB)
void gemm_bt(const unsigned short* __restrict__ A,
             const unsigned short* __restrict__ Wt,
             void* __restrict__ C_, int M, int N, int K)
{
    __shared__ __align__(16) unsigned short As[MI * 32 * 64];
    __shared__ __align__(16) unsigned short Bs[128 * 64];

    const int tid  = threadIdx.x;
    const int wave = tid >> 6;
    const int lane = tid & 63;
    const int quad = lane >> 4;
    const int c0   = lane & 15;
    const int m0 = blockIdx.y * (MI * 32);
    const int n0 = blockIdx.x * 128;
    const int wm = (wave >> 1) * (MI * 16);
    const int wn = (wave & 1) * 64;

    const int lrow   = lane >> 3;
    const int gchunk = (lane & 7) ^ lrow;
    const int goff   = gchunk * 8;

    f32x4 acc[MI][4];
#pragma unroll
    for (int i = 0; i < MI; i++)
#pragma unroll
        for (int j = 0; j < 4; j++) acc[i][j] = vzero();

    for (int k0 = 0; k0 < K; k0 += 64) {
        __syncthreads();
#pragma unroll
        for (int p = 0; p < MI; p++) {
            int r0 = p * 32 + wave * 8;
            GLD16(&A[(size_t)(m0 + r0 + lrow) * K + k0 + goff], &As[r0 * 64]);
        }
#pragma unroll
        for (int p = 0; p < 4; p++) {
            int r0 = p * 32 + wave * 8;
            GLD16(&Wt[(size_t)(n0 + r0 + lrow) * K + k0 + goff], &Bs[r0 * 64]);
        }
        __syncthreads();
#pragma unroll
        for (int kk = 0; kk < 2; kk++) {
            const int pos = ((kk * 4 + quad) ^ (c0 & 7)) * 8;
            bf16x8 af[MI], bfr[4];
#pragma unroll
            for (int i = 0; i < MI; i++)
                af[i] = *(const bf16x8*)&As[(wm + i * 16 + c0) * 64 + pos];
#pragma unroll
            for (int j = 0; j < 4; j++)
                bfr[j] = *(const bf16x8*)&Bs[(wn + j * 16 + c0) * 64 + pos];
#pragma unroll
            for (int i = 0; i < MI; i++)
#pragma unroll
                for (int j = 0; j < 4; j++)
                    acc[i][j] = mfma16(af[i], bfr[j], acc[i][j]);
        }
    }

    // C/D layout: col=lane&15, row=quad*4+reg  [verified m89/m91 + R3..R14 pass]
#pragma unroll
    for (int i = 0; i < MI; i++)
#pragma unroll
        for (int j = 0; j < 4; j++)
#pragma unroll
            for (int r = 0; r < 4; r++) {
                int row  = m0 + wm + i * 16 + quad * 4 + r;
                int colg = n0 + wn + j * 16 + c0;
                if (C32) ((float*)C_)[(size_t)row * N + colg] = acc[i][j][r];
                else ((unsigned short*)C_)[(size_t)row * N + colg] = f2bf(acc[i][j][r]);
            }
}

// ---------- fused RoPE + V-transpose + Wout convert (R9/R12-proven) ----------
__global__ __launch_bounds__(256)
void rope_vtrans(const unsigned short* __restrict__ qkv,
                 const int* __restrict__ pos,
                 unsigned short* __restrict__ Qb,
                 unsigned short* __restrict__ Kb,
                 unsigned short* __restrict__ Vt,
                 const float* __restrict__ wout,
                 unsigned short* __restrict__ woutb)
{
    __shared__ unsigned short T[256 * 64];
    const int id = blockIdx.x;
    if (id < 8192) {
        int tid = id * 256 + threadIdx.x;
        int d2 = tid & 31;
        int h  = (tid >> 5) & 15;
        int l  = (tid >> 9) & 2047;
        int b  = tid >> 20;
        size_t row = (size_t)(b * 2048 + l) * 3072;
        int col = h * 64 + 2 * d2;
        float inv_freq = exp2f((float)(-2 * d2) * (13.287712379549449f / 64.0f));
        float f = (float)pos[b * 2048 + l] * inv_freq;
        float s, c;
        sincosf(f, &s, &c);
        unsigned qw = *(const unsigned*)&qkv[row + col];
        unsigned kw = *(const unsigned*)&qkv[row + 1024 + col];
        float q1 = bf2f((unsigned short)qw), q2 = bf2f((unsigned short)(qw >> 16));
        float k1 = bf2f((unsigned short)kw), k2 = bf2f((unsigned short)(kw >> 16));
        const float qs = 0.18033688011112042f;   // 0.125 * log2(e)
        size_t o = ((size_t)((b * 16 + h) * 2048 + l)) * 64 + 2 * d2;
        *(unsigned*)&Qb[o] = pack2((q1 * c - q2 * s) * qs, (q1 * s + q2 * c) * qs);
        *(unsigned*)&Kb[o] = pack2(k1 * c - k2 * s, k1 * s + k2 * c);
    } else if (id < 8448) {
        const int id2 = id - 8192;
        const int t = threadIdx.x;
        const int l0 = (id2 & 7) * 256, h = (id2 >> 3) & 15, b = id2 >> 7;
#pragma unroll
        for (int i = 0; i < 8; i++) {
            int c = t + i * 256;
            int r = c >> 3, c8 = c & 7;
            int p = (c8 + (r >> 3)) & 7;
            *(uint4*)&T[r * 64 + p * 8] =
                *(const uint4*)&qkv[(size_t)(b * 2048 + l0 + r) * 3072 + 2048 + h * 64 + c8 * 8];
        }
        __syncthreads();
#pragma unroll
        for (int i = 0; i < 8; i++) {
            int c = t + i * 256;
            int dh = c >> 5, lc = c & 31;
            int blk = dh >> 3;
            unsigned short tmp[8];
#pragma unroll
            for (int j = 0; j < 8; j++) {
                int l = lc * 8 + j;
                int p = (blk + lc) & 7;
                tmp[j] = T[l * 64 + p * 8 + (dh & 7)];
            }
            *(uint4*)&Vt[((size_t)(b * 16 + h) * 64 + dh) * 2048 + l0 + lc * 8] = *(uint4*)tmp;
        }
    } else {
        int i = (id - 8448) * 256 + threadIdx.x;   // < 131072 chunks of Wout
        const float4* p = (const float4*)wout + (size_t)i * 2;
        float4 f0 = p[0], f1 = p[1];
        uint4 o;
        o.x = pack2(f0.x, f0.y); o.y = pack2(f0.z, f0.w);
        o.z = pack2(f1.x, f1.y); o.w = pack2(f1.z, f1.w);
        ((uint4*)woutb)[i] = o;
    }
}

// ---------- causal flash attention: paired q-tiles, double-wide KV staging ----------
// Pair (jp, 31-jp) = exactly 33 compute-tiles/block (R12-proven balance).
// NEW: stage TWO kv-tiles per barrier round, and replace the per-tile Ps barrier
// with a wave-level fence: Ps rows [wave*16,wave*16+16) are written AND read by
// the same wave only (write row=wave*16+quad*4+r, read row=wave*16+c0), so only
// within-wave DS ordering is needed — "s_waitcnt lgkmcnt(0)" + memory clobber
// (compiler fence vs the R1 TBAA-hoist NaN; HW DS pipe is in-order per wave).
// Barriers: 3/tile -> 1/tile. LDS 64KB -> exactly 2 blocks/CU (grid 512).
__global__ __launch_bounds__(256, 2)
void attn(const unsigned short* __restrict__ Q,
          const unsigned short* __restrict__ Kb,
          const unsigned short* __restrict__ Vt,   // [b,h,dh,l]
          unsigned short* __restrict__ O)          // [B, L, H*64]
{
    __shared__ unsigned short QsA[64 * 64];
    __shared__ unsigned short QsB[64 * 64];
    __shared__ unsigned short Ks[2][64 * 64];
    __shared__ unsigned short Vts[2][64 * 64];  // [dh][key]
    __shared__ unsigned short PsA[64 * 64];
    __shared__ unsigned short PsB[64 * 64];

    const int tid  = threadIdx.x;
    const int wave = tid >> 6;
    const int lane = tid & 63;
    const int quad = lane >> 4;
    const int c0   = lane & 15;
    const int id = blockIdx.x;          // 512 blocks
    const int jp = id >> 5;             // pair index 0..15
    const int h  = id & 15;
    const int b  = (id >> 4) & 1;
    const int qtA = jp, qtB = 31 - jp;  // qtA < qtB ; qtB >= 16
    const size_t headoff = ((size_t)(b * 16 + h)) * 2048 * 64;
    const int q0A = qtA * 64, q0B = qtB * 64;
    const float C = 11.541560327111707f;     // 8 * log2(e)

    const int ca = tid, cb2 = tid + 256;
    const int ra = ca >> 3, c8a = ca & 7;
    const int rb = cb2 >> 3, c8b = cb2 & 7;
    const int la = ra * 64 + (c8a ^ (ra & 7)) * 8;   // XOR-swizzled staging offsets
    const int lb = rb * 64 + (c8b ^ (rb & 7)) * 8;

    bf16x8 ones;
#pragma unroll
    for (int j = 0; j < 8; j++) ones[j] = (__bf16)1.0f;

    uint4 kr[2][2], vr[2][2];
#pragma unroll
    for (int t = 0; t < 2; t++) {       // prefetch tiles 0,1 (qtB>=16 so both exist)
        size_t ko = headoff + (size_t)t * 4096;
        kr[t][0] = *(const uint4*)&Kb[ko + (size_t)ra * 64 + c8a * 8];
        kr[t][1] = *(const uint4*)&Kb[ko + (size_t)rb * 64 + c8b * 8];
        vr[t][0] = *(const uint4*)&Vt[headoff + (size_t)ra * 2048 + t * 64 + c8a * 8];
        vr[t][1] = *(const uint4*)&Vt[headoff + (size_t)rb * 2048 + t * 64 + c8b * 8];
    }
    // stage both Q tiles (swizzled)
    *(uint4*)&QsA[la] = *(const uint4*)&Q[headoff + (size_t)(q0A + ra) * 64 + c8a * 8];
    *(uint4*)&QsA[lb] = *(const uint4*)&Q[headoff + (size_t)(q0A + rb) * 64 + c8b * 8];
    *(uint4*)&QsB[la] = *(const uint4*)&Q[headoff + (size_t)(q0B + ra) * 64 + c8a * 8];
    *(uint4*)&QsB[lb] = *(const uint4*)&Q[headoff + (size_t)(q0B + rb) * 64 + c8b * 8];

    f32x4 oA[4], oB[4];
#pragma unroll
    for (int j = 0; j < 4; j++) { oA[j] = vzero(); oB[j] = vzero(); }
    f32x4 laccA = vzero(), laccB = vzero();

    for (int kt = 0; kt <= qtB; kt += 2) {
        const bool has2 = (kt + 1 <= qtB);
        __syncthreads();                 // all waves done with Ks/Vts of prev round
        *(uint4*)&Ks[0][la] = kr[0][0];
        *(uint4*)&Ks[0][lb] = kr[0][1];
        *(uint4*)&Vts[0][la] = vr[0][0];
        *(uint4*)&Vts[0][lb] = vr[0][1];
        if (has2) {
            *(uint4*)&Ks[1][la] = kr[1][0];
            *(uint4*)&Ks[1][lb] = kr[1][1];
            *(uint4*)&Vts[1][la] = vr[1][0];
            *(uint4*)&Vts[1][lb] = vr[1][1];
        }
        __syncthreads();                 // staging visible
        if (kt + 2 <= qtB) {             // prefetch tile kt+2
            size_t ko = headoff + (size_t)(kt + 2) * 4096;
            kr[0][0] = *(const uint4*)&Kb[ko + (size_t)ra * 64 + c8a * 8];
            kr[0][1] = *(const uint4*)&Kb[ko + (size_t)rb * 64 + c8b * 8];
            vr[0][0] = *(const uint4*)&Vt[headoff + (size_t)ra * 2048 + (kt + 2) * 64 + c8a * 8];
            vr[0][1] = *(const uint4*)&Vt[headoff + (size_t)rb * 2048 + (kt + 2) * 64 + c8b * 8];
        }
        if (kt + 3 <= qtB) {             // prefetch tile kt+3
            size_t ko = headoff + (size_t)(kt + 3) * 4096;
            kr[1][0] = *(const uint4*)&Kb[ko + (size_t)ra * 64 + c8a * 8];
            kr[1][1] = *(const uint4*)&Kb[ko + (size_t)rb * 64 + c8b * 8];
            vr[1][0] = *(const uint4*)&Vt[headoff + (size_t)ra * 2048 + (kt + 3) * 64 + c8a * 8];
            vr[1][1] = *(const uint4*)&Vt[headoff + (size_t)rb * 2048 + (kt + 3) * 64 + c8b * 8];
        }

#pragma unroll
        for (int t = 0; t < 2; t++) {
            if (t == 1 && !has2) break;
            const int cur = kt + t;
            const bool doA = (cur <= qtA);   // block-uniform

            // ---- S for tile B
            {
                f32x4 s[4];
#pragma unroll
                for (int nj = 0; nj < 4; nj++) s[nj] = vzero();
#pragma unroll
                for (int kk = 0; kk < 2; kk++) {
                    const int pos = ((kk * 4 + quad) ^ (c0 & 7)) * 8;
                    bf16x8 aq = *(const bf16x8*)&QsB[(wave * 16 + c0) * 64 + pos];
#pragma unroll
                    for (int nj = 0; nj < 4; nj++) {
                        bf16x8 bk = *(const bf16x8*)&Ks[t][(nj * 16 + c0) * 64 + pos];
                        s[nj] = mfma16(aq, bk, s[nj]);
                    }
                }
                if (cur == qtB) {
#pragma unroll
                    for (int nj = 0; nj < 4; nj++)
#pragma unroll
                        for (int r = 0; r < 4; r++) {
                            int key  = nj * 16 + c0;
                            int qrow = wave * 16 + quad * 4 + r;
                            if (key > qrow) s[nj][r] = -1e38f;
                        }
                }
#pragma unroll
                for (int nj = 0; nj < 4; nj++)
#pragma unroll
                    for (int r = 0; r < 4; r++) {
                        union { float f; unsigned u; } pv;
                        pv.f = __builtin_amdgcn_exp2f(s[nj][r] - C);
                        int row = wave * 16 + quad * 4 + r;
                        int col = nj * 16 + c0;
                        int pp = ((col >> 3) + row) & 7;
                        PsB[row * 64 + pp * 8 + (col & 7)] = (unsigned short)(pv.u >> 16);
                    }
            }
            // ---- S for tile A
            if (doA) {
                f32x4 s[4];
#pragma unroll
                for (int nj = 0; nj < 4; nj++) s[nj] = vzero();
#pragma unroll
                for (int kk = 0; kk < 2; kk++) {
                    const int pos = ((kk * 4 + quad) ^ (c0 & 7)) * 8;
                    bf16x8 aq = *(const bf16x8*)&QsA[(wave * 16 + c0) * 64 + pos];
#pragma unroll
                    for (int nj = 0; nj < 4; nj++) {
                        bf16x8 bk = *(const bf16x8*)&Ks[t][(nj * 16 + c0) * 64 + pos];
                        s[nj] = mfma16(aq, bk, s[nj]);
                    }
                }
                if (cur == qtA) {
#pragma unroll
                    for (int nj = 0; nj < 4; nj++)
#pragma unroll
                        for (int r = 0; r < 4; r++) {
                            int key  = nj * 16 + c0;
                            int qrow = wave * 16 + quad * 4 + r;
                            if (key > qrow) s[nj][r] = -1e38f;
                        }
                }
#pragma unroll
                for (int nj = 0; nj < 4; nj++)
#pragma unroll
                    for (int r = 0; r < 4; r++) {
                        union { float f; unsigned u; } pv;
                        pv.f = __builtin_amdgcn_exp2f(s[nj][r] - C);
                        int row = wave * 16 + quad * 4 + r;
                        int col = nj * 16 + c0;
                        int pp = ((col >> 3) + row) & 7;
                        PsA[row * 64 + pp * 8 + (col & 7)] = (unsigned short)(pv.u >> 16);
                    }
            }
            // wave-private Ps round-trip: HW DS in-order + retire wait; memory
            // clobber stops the compiler hoisting the bf16x8 loads (R1 lesson).
            asm volatile("s_waitcnt lgkmcnt(0)" ::: "memory");

            // ---- PV for tile B
#pragma unroll
            for (int kk = 0; kk < 2; kk++) {
                const int pos = ((kk * 4 + quad) ^ (c0 & 7)) * 8;
                int prow = wave * 16 + c0;
                int pp = ((kk * 4 + quad) + prow) & 7;
                bf16x8 ap = *(const bf16x8*)&PsB[prow * 64 + pp * 8];
                laccB = mfma16(ap, ones, laccB);
#pragma unroll
                for (int cj = 0; cj < 4; cj++) {
                    bf16x8 bv = *(const bf16x8*)&Vts[t][(cj * 16 + c0) * 64 + pos];
                    oB[cj] = mfma16(ap, bv, oB[cj]);
                }
            }
            // ---- PV for tile A
            if (doA) {
#pragma unroll
                for (int kk = 0; kk < 2; kk++) {
                    const int pos = ((kk * 4 + quad) ^ (c0 & 7)) * 8;
                    int prow = wave * 16 + c0;
                    int pp = ((kk * 4 + quad) + prow) & 7;
                    bf16x8 ap = *(const bf16x8*)&PsA[prow * 64 + pp * 8];
                    laccA = mfma16(ap, ones, laccA);
#pragma unroll
                    for (int cj = 0; cj < 4; cj++) {
                        bf16x8 bv = *(const bf16x8*)&Vts[t][(cj * 16 + c0) * 64 + pos];
                        oA[cj] = mfma16(ap, bv, oA[cj]);
                    }
                }
            }
        }
    }

    // epilogue: both tiles
#pragma unroll
    for (int r = 0; r < 4; r++) {
        float invA = 1.0f / laccA[r];
        float invB = 1.0f / laccB[r];
        int qlA = q0A + wave * 16 + quad * 4 + r;
        int qlB = q0B + wave * 16 + quad * 4 + r;
        size_t baseA = ((size_t)b * 2048 + qlA) * 1024 + h * 64;
        size_t baseB = ((size_t)b * 2048 + qlB) * 1024 + h * 64;
#pragma unroll
        for (int cj = 0; cj < 4; cj++) {
            O[baseA + cj * 16 + c0] = f2bf(oA[cj][r] * invA);
            O[baseB + cj * 16 + c0] = f2bf(oB[cj][r] * invB);
        }
    }
}

// ---------- launch ----------
extern "C" void kernel_launch(void* const* d_in, const int* in_sizes, int n_in,
                              void* d_out, int out_size, void* d_ws, size_t ws_size,
                              hipStream_t stream) {
    const int* pos = (const int*)d_in[3];
    // d_in[4] = causal tril mask: applied analytically, not read
    // Input dtype hard-coded f32 (proven R3-R14)

    // ws layout (lifetime-aliased, R9/R12-proven):
    //  A: xb -> Qb ; B: wqkvb -> Kb ; C: Vt ; D: qkv -> Ob ; E: woutb
    unsigned short* regA = (unsigned short*)d_ws;
    unsigned short* regB = regA + (size_t)4096 * 1024;
    unsigned short* regC = regB + (size_t)4096 * 1024;
    unsigned short* regD = regC + (size_t)4096 * 1024;
    unsigned short* regE = regD + (size_t)4096 * 3072;

    unsigned short* xb    = regA;
    unsigned short* wqkvb = regB;
    unsigned short* qkv   = regD;
    unsigned short* Qb    = regA;
    unsigned short* Kb    = regB;
    unsigned short* Vt    = regC;
    unsigned short* Ob    = regD;
    unsigned short* woutb = regE;

    convert_xw<<<3584, 256, 0, stream>>>((const float*)d_in[0], (const float*)d_in[1],
                                         xb, wqkvb);
    // 1) qkv = x @ Wqkv^T  (128x128 tiles, 768 blocks — R12-proven launch)
    gemm_bt<4, 0, 4><<<dim3(24, 32), 256, 0, stream>>>(xb, wqkvb, qkv, 4096, 3072, 1024);
    // 2) RoPE Q,K + V transpose + Wout convert (fused — R9-proven)
    rope_vtrans<<<8960, 256, 0, stream>>>(qkv, pos, Qb, Kb, Vt,
                                          (const float*)d_in[2], woutb);
    // 3) causal flash attention — paired q-tiles, double-wide KV, 1 barrier/tile
    attn<<<512, 256, 0, stream>>>(Qb, Kb, Vt, Ob);
    // 4) out = Ob @ Wout^T  (64x128 tiles, 512 blocks, f32 out — R12-proven launch)
    gemm_bt<2, 1, 3><<<dim3(8, 64), 256, 0, stream>>>(Ob, woutb, d_out, 4096, 1024, 1024);
}

// Round 16
// 193.965 us; speedup vs baseline: 1.1574x; 1.1574x over previous
//
#include <hip/hip_runtime.h>
#include <hip/hip_bf16.h>
#include <math.h>

// ---------- common helpers ----------
typedef float f32x4 __attribute__((ext_vector_type(4)));
typedef __bf16 bf16x8 __attribute__((ext_vector_type(8)));

__device__ inline f32x4 mfma16(bf16x8 a, bf16x8 b, f32x4 c) {
    return __builtin_amdgcn_mfma_f32_16x16x32_bf16(a, b, c, 0, 0, 0);
}
__device__ inline unsigned short f2bf(float f) {   // RNE f32 -> bf16
    union { float f; unsigned u; } v; v.f = f;
    unsigned r = v.u + 0x7fffu + ((v.u >> 16) & 1u);
    return (unsigned short)(r >> 16);
}
__device__ inline float bf2f(unsigned short b) {
    union { unsigned u; float f; } v; v.u = ((unsigned)b) << 16;
    return v.f;
}
__device__ inline unsigned pack2(float a, float b) {
    return (unsigned)f2bf(a) | ((unsigned)f2bf(b) << 16);
}
__device__ inline f32x4 vzero() { f32x4 z = {0.f, 0.f, 0.f, 0.f}; return z; }

// async global->LDS, 16B per lane; LDS dest = wave-uniform base + lane*16 (m97/m104)
#define GLD16(gptr, lptr)                                                            \
    __builtin_amdgcn_global_load_lds(                                                \
        (const __attribute__((address_space(1))) unsigned int*)(const void*)(gptr),  \
        (__attribute__((address_space(3))) unsigned int*)(void*)(lptr), 16, 0, 0)

// ---------- convert x, Wqkv (f32, proven R3-R15) -> bf16; 3584 blocks exact ----------
__global__ __launch_bounds__(256)
void convert_xw(const float* __restrict__ x, const float* __restrict__ wqkv,
                unsigned short* __restrict__ xb, unsigned short* __restrict__ wqkvb)
{
    int i = blockIdx.x * 256 + threadIdx.x;   // < 917504
    const float* src; unsigned short* dst; int off;
    if (i < 524288) { src = x;    dst = xb;    off = i; }
    else            { src = wqkv; dst = wqkvb; off = i - 524288; }
    const float4* p = (const float4*)src + (size_t)off * 2;
    float4 f0 = p[0], f1 = p[1];
    uint4 o;
    o.x = pack2(f0.x, f0.y); o.y = pack2(f0.z, f0.w);
    o.z = pack2(f1.x, f1.y); o.w = pack2(f1.z, f1.w);
    ((uint4*)dst)[off] = o;
}

// ---------- GEMM: C[M,N] = A[M,K] * W[N,K]^T  (R12-proven, dim3 grid) ----------
template<int MI, int C32, int WPB>
__global__ __launch_bounds__(256, WPB)
void gemm_bt(const unsigned short* __restrict__ A,
             const unsigned short* __restrict__ Wt,
             void* __restrict__ C_, int M, int N, int K)
{
    __shared__ __align__(16) unsigned short As[MI * 32 * 64];
    __shared__ __align__(16) unsigned short Bs[128 * 64];

    const int tid  = threadIdx.x;
    const int wave = tid >> 6;
    const int lane = tid & 63;
    const int quad = lane >> 4;
    const int c0   = lane & 15;
    const int m0 = blockIdx.y * (MI * 32);
    const int n0 = blockIdx.x * 128;
    const int wm = (wave >> 1) * (MI * 16);
    const int wn = (wave & 1) * 64;

    const int lrow   = lane >> 3;
    const int gchunk = (lane & 7) ^ lrow;
    const int goff   = gchunk * 8;

    f32x4 acc[MI][4];
#pragma unroll
    for (int i = 0; i < MI; i++)
#pragma unroll
        for (int j = 0; j < 4; j++) acc[i][j] = vzero();

    for (int k0 = 0; k0 < K; k0 += 64) {
        __syncthreads();
#pragma unroll
        for (int p = 0; p < MI; p++) {
            int r0 = p * 32 + wave * 8;
            GLD16(&A[(size_t)(m0 + r0 + lrow) * K + k0 + goff], &As[r0 * 64]);
        }
#pragma unroll
        for (int p = 0; p < 4; p++) {
            int r0 = p * 32 + wave * 8;
            GLD16(&Wt[(size_t)(n0 + r0 + lrow) * K + k0 + goff], &Bs[r0 * 64]);
        }
        __syncthreads();
#pragma unroll
        for (int kk = 0; kk < 2; kk++) {
            const int pos = ((kk * 4 + quad) ^ (c0 & 7)) * 8;
            bf16x8 af[MI], bfr[4];
#pragma unroll
            for (int i = 0; i < MI; i++)
                af[i] = *(const bf16x8*)&As[(wm + i * 16 + c0) * 64 + pos];
#pragma unroll
            for (int j = 0; j < 4; j++)
                bfr[j] = *(const bf16x8*)&Bs[(wn + j * 16 + c0) * 64 + pos];
#pragma unroll
            for (int i = 0; i < MI; i++)
#pragma unroll
                for (int j = 0; j < 4; j++)
                    acc[i][j] = mfma16(af[i], bfr[j], acc[i][j]);
        }
    }

    // C/D layout: col=lane&15, row=quad*4+reg  [verified m89/m91 + R3..R15 pass]
#pragma unroll
    for (int i = 0; i < MI; i++)
#pragma unroll
        for (int j = 0; j < 4; j++)
#pragma unroll
            for (int r = 0; r < 4; r++) {
                int row  = m0 + wm + i * 16 + quad * 4 + r;
                int colg = n0 + wn + j * 16 + c0;
                if (C32) ((float*)C_)[(size_t)row * N + colg] = acc[i][j][r];
                else ((unsigned short*)C_)[(size_t)row * N + colg] = f2bf(acc[i][j][r]);
            }
}

// ---------- fused RoPE + V-transpose + Wout convert (R9/R12-proven) ----------
__global__ __launch_bounds__(256)
void rope_vtrans(const unsigned short* __restrict__ qkv,
                 const int* __restrict__ pos,
                 unsigned short* __restrict__ Qb,
                 unsigned short* __restrict__ Kb,
                 unsigned short* __restrict__ Vt,
                 const float* __restrict__ wout,
                 unsigned short* __restrict__ woutb)
{
    __shared__ unsigned short T[256 * 64];
    const int id = blockIdx.x;
    if (id < 8192) {
        int tid = id * 256 + threadIdx.x;
        int d2 = tid & 31;
        int h  = (tid >> 5) & 15;
        int l  = (tid >> 9) & 2047;
        int b  = tid >> 20;
        size_t row = (size_t)(b * 2048 + l) * 3072;
        int col = h * 64 + 2 * d2;
        float inv_freq = exp2f((float)(-2 * d2) * (13.287712379549449f / 64.0f));
        float f = (float)pos[b * 2048 + l] * inv_freq;
        float s, c;
        sincosf(f, &s, &c);
        unsigned qw = *(const unsigned*)&qkv[row + col];
        unsigned kw = *(const unsigned*)&qkv[row + 1024 + col];
        float q1 = bf2f((unsigned short)qw), q2 = bf2f((unsigned short)(qw >> 16));
        float k1 = bf2f((unsigned short)kw), k2 = bf2f((unsigned short)(kw >> 16));
        const float qs = 0.18033688011112042f;   // 0.125 * log2(e)
        size_t o = ((size_t)((b * 16 + h) * 2048 + l)) * 64 + 2 * d2;
        *(unsigned*)&Qb[o] = pack2((q1 * c - q2 * s) * qs, (q1 * s + q2 * c) * qs);
        *(unsigned*)&Kb[o] = pack2(k1 * c - k2 * s, k1 * s + k2 * c);
    } else if (id < 8448) {
        const int id2 = id - 8192;
        const int t = threadIdx.x;
        const int l0 = (id2 & 7) * 256, h = (id2 >> 3) & 15, b = id2 >> 7;
#pragma unroll
        for (int i = 0; i < 8; i++) {
            int c = t + i * 256;
            int r = c >> 3, c8 = c & 7;
            int p = (c8 + (r >> 3)) & 7;
            *(uint4*)&T[r * 64 + p * 8] =
                *(const uint4*)&qkv[(size_t)(b * 2048 + l0 + r) * 3072 + 2048 + h * 64 + c8 * 8];
        }
        __syncthreads();
#pragma unroll
        for (int i = 0; i < 8; i++) {
            int c = t + i * 256;
            int dh = c >> 5, lc = c & 31;
            int blk = dh >> 3;
            unsigned short tmp[8];
#pragma unroll
            for (int j = 0; j < 8; j++) {
                int l = lc * 8 + j;
                int p = (blk + lc) & 7;
                tmp[j] = T[l * 64 + p * 8 + (dh & 7)];
            }
            *(uint4*)&Vt[((size_t)(b * 16 + h) * 64 + dh) * 2048 + l0 + lc * 8] = *(uint4*)tmp;
        }
    } else {
        int i = (id - 8448) * 256 + threadIdx.x;   // < 131072 chunks of Wout
        const float4* p = (const float4*)wout + (size_t)i * 2;
        float4 f0 = p[0], f1 = p[1];
        uint4 o;
        o.x = pack2(f0.x, f0.y); o.y = pack2(f0.z, f0.w);
        o.z = pack2(f1.x, f1.y); o.w = pack2(f1.z, f1.w);
        ((uint4*)woutb)[i] = o;
    }
}

// ---------- causal flash attention: paired q-tiles (j, 31-j) — R12 structure ----------
// R12-proven except ONE change: the Ps-visibility __syncthreads() is replaced by a
// wave-level fence. Ps rows [wave*16,wave*16+16) are written (row=wave*16+quad*4+r)
// and read (row=wave*16+c0) by the SAME wave only; "s_waitcnt lgkmcnt(0)" + memory
// clobber gives within-wave DS ordering + blocks TBAA hoisting (correctness proven
// on HW in R15, absmax 0.0156). Barriers per kv-tile: 3 -> 2.
// R15 lesson: no double-wide staging / indexed register arrays (scratch spill).
__global__ __launch_bounds__(256, 2)
void attn(const unsigned short* __restrict__ Q,
          const unsigned short* __restrict__ Kb,
          const unsigned short* __restrict__ Vt,   // [b,h,dh,l]
          unsigned short* __restrict__ O)          // [B, L, H*64]
{
    __shared__ unsigned short QsA[64 * 64];
    __shared__ unsigned short QsB[64 * 64];
    __shared__ unsigned short Ks[64 * 64];
    __shared__ unsigned short Vts[64 * 64];  // [dh][key]
    __shared__ unsigned short PsA[64 * 64];
    __shared__ unsigned short PsB[64 * 64];

    const int tid  = threadIdx.x;
    const int wave = tid >> 6;
    const int lane = tid & 63;
    const int quad = lane >> 4;
    const int c0   = lane & 15;
    const int id = blockIdx.x;          // 512 blocks
    const int jp = id >> 5;             // pair index 0..15
    const int h  = id & 15;
    const int b  = (id >> 4) & 1;
    const int qtA = jp, qtB = 31 - jp;  // qtA < qtB
    const size_t headoff = ((size_t)(b * 16 + h)) * 2048 * 64;
    const int q0A = qtA * 64, q0B = qtB * 64;
    const float C = 11.541560327111707f;     // 8 * log2(e)

    const int ca = tid, cb2 = tid + 256;
    const int ra = ca >> 3, c8a = ca & 7;
    const int rb = cb2 >> 3, c8b = cb2 & 7;
    const int la = ra * 64 + (c8a ^ (ra & 7)) * 8;   // XOR-swizzled staging offsets
    const int lb = rb * 64 + (c8b ^ (rb & 7)) * 8;

    bf16x8 ones;
#pragma unroll
    for (int j = 0; j < 8; j++) ones[j] = (__bf16)1.0f;

    uint4 kreg0, kreg1, vreg0, vreg1;
    {   // prefetch tile kt=0
        kreg0 = *(const uint4*)&Kb[headoff + (size_t)ra * 64 + c8a * 8];
        kreg1 = *(const uint4*)&Kb[headoff + (size_t)rb * 64 + c8b * 8];
        vreg0 = *(const uint4*)&Vt[headoff + (size_t)ra * 2048 + c8a * 8];
        vreg1 = *(const uint4*)&Vt[headoff + (size_t)rb * 2048 + c8b * 8];
    }
    // stage both Q tiles (swizzled)
    *(uint4*)&QsA[la] = *(const uint4*)&Q[headoff + (size_t)(q0A + ra) * 64 + c8a * 8];
    *(uint4*)&QsA[lb] = *(const uint4*)&Q[headoff + (size_t)(q0A + rb) * 64 + c8b * 8];
    *(uint4*)&QsB[la] = *(const uint4*)&Q[headoff + (size_t)(q0B + ra) * 64 + c8a * 8];
    *(uint4*)&QsB[lb] = *(const uint4*)&Q[headoff + (size_t)(q0B + rb) * 64 + c8b * 8];

    f32x4 oA[4], oB[4];
#pragma unroll
    for (int j = 0; j < 4; j++) { oA[j] = vzero(); oB[j] = vzero(); }
    f32x4 laccA = vzero(), laccB = vzero();

    for (int kt = 0; kt <= qtB; kt++) {
        __syncthreads();                 // prev iter's Ks/Vts/Ps reads complete
        *(uint4*)&Ks[la] = kreg0;
        *(uint4*)&Ks[lb] = kreg1;
        *(uint4*)&Vts[la] = vreg0;
        *(uint4*)&Vts[lb] = vreg1;
        __syncthreads();                 // staging visible
        if (kt < qtB) {                  // prefetch next (Kb stride 4096, Vt stride 64)
            size_t k1o = headoff + (size_t)(kt + 1) * 4096;
            kreg0 = *(const uint4*)&Kb[k1o + (size_t)ra * 64 + c8a * 8];
            kreg1 = *(const uint4*)&Kb[k1o + (size_t)rb * 64 + c8b * 8];
            vreg0 = *(const uint4*)&Vt[headoff + (size_t)ra * 2048 + (kt + 1) * 64 + c8a * 8];
            vreg1 = *(const uint4*)&Vt[headoff + (size_t)rb * 2048 + (kt + 1) * 64 + c8b * 8];
        }
        const bool doA = (kt <= qtA);    // block-uniform

        // ---- S for tile B (always live)
        {
            f32x4 s[4];
#pragma unroll
            for (int nj = 0; nj < 4; nj++) s[nj] = vzero();
#pragma unroll
            for (int kk = 0; kk < 2; kk++) {
                const int pos = ((kk * 4 + quad) ^ (c0 & 7)) * 8;
                bf16x8 aq = *(const bf16x8*)&QsB[(wave * 16 + c0) * 64 + pos];
#pragma unroll
                for (int nj = 0; nj < 4; nj++) {
                    bf16x8 bk = *(const bf16x8*)&Ks[(nj * 16 + c0) * 64 + pos];
                    s[nj] = mfma16(aq, bk, s[nj]);
                }
            }
            if (kt == qtB) {
#pragma unroll
                for (int nj = 0; nj < 4; nj++)
#pragma unroll
                    for (int r = 0; r < 4; r++) {
                        int key  = nj * 16 + c0;
                        int qrow = wave * 16 + quad * 4 + r;
                        if (key > qrow) s[nj][r] = -1e38f;
                    }
            }
#pragma unroll
            for (int nj = 0; nj < 4; nj++)
#pragma unroll
                for (int r = 0; r < 4; r++) {
                    union { float f; unsigned u; } pv;
                    pv.f = __builtin_amdgcn_exp2f(s[nj][r] - C);
                    int row = wave * 16 + quad * 4 + r;
                    int col = nj * 16 + c0;
                    int pp = ((col >> 3) + row) & 7;
                    PsB[row * 64 + pp * 8 + (col & 7)] = (unsigned short)(pv.u >> 16);
                }
        }
        // ---- S for tile A (first qtA+1 iters)
        if (doA) {
            f32x4 s[4];
#pragma unroll
            for (int nj = 0; nj < 4; nj++) s[nj] = vzero();
#pragma unroll
            for (int kk = 0; kk < 2; kk++) {
                const int pos = ((kk * 4 + quad) ^ (c0 & 7)) * 8;
                bf16x8 aq = *(const bf16x8*)&QsA[(wave * 16 + c0) * 64 + pos];
#pragma unroll
                for (int nj = 0; nj < 4; nj++) {
                    bf16x8 bk = *(const bf16x8*)&Ks[(nj * 16 + c0) * 64 + pos];
                    s[nj] = mfma16(aq, bk, s[nj]);
                }
            }
            if (kt == qtA) {
#pragma unroll
                for (int nj = 0; nj < 4; nj++)
#pragma unroll
                    for (int r = 0; r < 4; r++) {
                        int key  = nj * 16 + c0;
                        int qrow = wave * 16 + quad * 4 + r;
                        if (key > qrow) s[nj][r] = -1e38f;
                    }
            }
#pragma unroll
            for (int nj = 0; nj < 4; nj++)
#pragma unroll
                for (int r = 0; r < 4; r++) {
                    union { float f; unsigned u; } pv;
                    pv.f = __builtin_amdgcn_exp2f(s[nj][r] - C);
                    int row = wave * 16 + quad * 4 + r;
                    int col = nj * 16 + c0;
                    int pp = ((col >> 3) + row) & 7;
                    PsA[row * 64 + pp * 8 + (col & 7)] = (unsigned short)(pv.u >> 16);
                }
        }
        // wave-private Ps round-trip: within-wave DS ordering only (proven R15)
        asm volatile("s_waitcnt lgkmcnt(0)" ::: "memory");

        // ---- PV for tile B
#pragma unroll
        for (int kk = 0; kk < 2; kk++) {
            const int pos = ((kk * 4 + quad) ^ (c0 & 7)) * 8;
            int prow = wave * 16 + c0;
            int pp = ((kk * 4 + quad) + prow) & 7;
            bf16x8 ap = *(const bf16x8*)&PsB[prow * 64 + pp * 8];
            laccB = mfma16(ap, ones, laccB);
#pragma unroll
            for (int cj = 0; cj < 4; cj++) {
                bf16x8 bv = *(const bf16x8*)&Vts[(cj * 16 + c0) * 64 + pos];
                oB[cj] = mfma16(ap, bv, oB[cj]);
            }
        }
        // ---- PV for tile A
        if (doA) {
#pragma unroll
            for (int kk = 0; kk < 2; kk++) {
                const int pos = ((kk * 4 + quad) ^ (c0 & 7)) * 8;
                int prow = wave * 16 + c0;
                int pp = ((kk * 4 + quad) + prow) & 7;
                bf16x8 ap = *(const bf16x8*)&PsA[prow * 64 + pp * 8];
                laccA = mfma16(ap, ones, laccA);
#pragma unroll
                for (int cj = 0; cj < 4; cj++) {
                    bf16x8 bv = *(const bf16x8*)&Vts[(cj * 16 + c0) * 64 + pos];
                    oA[cj] = mfma16(ap, bv, oA[cj]);
                }
            }
        }
    }

    // epilogue: both tiles
#pragma unroll
    for (int r = 0; r < 4; r++) {
        float invA = 1.0f / laccA[r];
        float invB = 1.0f / laccB[r];
        int qlA = q0A + wave * 16 + quad * 4 + r;
        int qlB = q0B + wave * 16 + quad * 4 + r;
        size_t baseA = ((size_t)b * 2048 + qlA) * 1024 + h * 64;
        size_t baseB = ((size_t)b * 2048 + qlB) * 1024 + h * 64;
#pragma unroll
        for (int cj = 0; cj < 4; cj++) {
            O[baseA + cj * 16 + c0] = f2bf(oA[cj][r] * invA);
            O[baseB + cj * 16 + c0] = f2bf(oB[cj][r] * invB);
        }
    }
}

// ---------- launch ----------
extern "C" void kernel_launch(void* const* d_in, const int* in_sizes, int n_in,
                              void* d_out, int out_size, void* d_ws, size_t ws_size,
                              hipStream_t stream) {
    const int* pos = (const int*)d_in[3];
    // d_in[4] = causal tril mask: applied analytically, not read
    // Input dtype hard-coded f32 (proven R3-R15)

    // ws layout (lifetime-aliased, R9/R12-proven):
    //  A: xb -> Qb ; B: wqkvb -> Kb ; C: Vt ; D: qkv -> Ob ; E: woutb
    unsigned short* regA = (unsigned short*)d_ws;
    unsigned short* regB = regA + (size_t)4096 * 1024;
    unsigned short* regC = regB + (size_t)4096 * 1024;
    unsigned short* regD = regC + (size_t)4096 * 1024;
    unsigned short* regE = regD + (size_t)4096 * 3072;

    unsigned short* xb    = regA;
    unsigned short* wqkvb = regB;
    unsigned short* qkv   = regD;
    unsigned short* Qb    = regA;
    unsigned short* Kb    = regB;
    unsigned short* Vt    = regC;
    unsigned short* Ob    = regD;
    unsigned short* woutb = regE;

    convert_xw<<<3584, 256, 0, stream>>>((const float*)d_in[0], (const float*)d_in[1],
                                         xb, wqkvb);
    // 1) qkv = x @ Wqkv^T  (128x128 tiles, 768 blocks — R12-proven launch)
    gemm_bt<4, 0, 4><<<dim3(24, 32), 256, 0, stream>>>(xb, wqkvb, qkv, 4096, 3072, 1024);
    // 2) RoPE Q,K + V transpose + Wout convert (fused — R9-proven)
    rope_vtrans<<<8960, 256, 0, stream>>>(qkv, pos, Qb, Kb, Vt,
                                          (const float*)d_in[2], woutb);
    // 3) causal flash attention — paired q-tiles, 2 barriers/tile (wave-fenced Ps)
    attn<<<512, 256, 0, stream>>>(Qb, Kb, Vt, Ob);
    // 4) out = Ob @ Wout^T  (64x128 tiles, 512 blocks, f32 out — R12-proven launch)
    gemm_bt<2, 1, 3><<<dim3(8, 64), 256, 0, stream>>>(Ob, woutb, d_out, 4096, 1024, 1024);
}